// Round 3
// baseline (455.374 us; speedup 1.0000x reference)
//
#include <hip/hip_runtime.h>
#include <hip/hip_bf16.h>
#include <cstdint>
#include <cstddef>

typedef __bf16 bf16_t;
typedef __bf16 bf16x4 __attribute__((ext_vector_type(4)));
typedef __bf16 bf16x8 __attribute__((ext_vector_type(8)));
typedef float f32x4 __attribute__((ext_vector_type(4)));
typedef float f32x16 __attribute__((ext_vector_type(16)));
typedef float f32x2 __attribute__((ext_vector_type(2)));
typedef int i32x4 __attribute__((ext_vector_type(4)));
typedef int i32x8 __attribute__((ext_vector_type(8)));

#define NROWS 8192
#define DFEAT 1024
#define BK 32
#define NBLK 64            // NROWS/128
#define TILE_B (128 * BK)  // bf16 elems per staged tile (8 KB)
#define F8TILE 8192        // fp8 bytes per staged 128x64 tile
#define NTRI (NBLK * (NBLK + 1) / 2)  // 2080 triangular tiles

typedef __attribute__((address_space(3))) unsigned int lds_uint;
typedef __attribute__((address_space(1))) const unsigned int glb_uint;

__device__ __forceinline__ float fast_tanh(float x) {
  float e = __expf(2.0f * x);
  return 1.0f - 2.0f * __builtin_amdgcn_rcpf(e + 1.0f);
}

// pack 4 floats -> 4 fp8 e4m3 bytes (OCP, HW cvt)
__device__ __forceinline__ unsigned pack_fp8x4(float a, float b, float c, float d) {
  unsigned v = 0;
  v = __builtin_amdgcn_cvt_pk_fp8_f32(a, b, v, false);
  v = __builtin_amdgcn_cvt_pk_fp8_f32(c, d, v, true);
  return v;
}

__global__ __launch_bounds__(256) void cast_kernel(const float* __restrict__ in,
                                                   bf16_t* __restrict__ out, int n4) {
  int i = blockIdx.x * 256 + threadIdx.x;
  if (i < n4) {
    float4 v = *(const float4*)(in + i * 4);
    bf16x4 o = {(bf16_t)v.x, (bf16_t)v.y, (bf16_t)v.z, (bf16_t)v.w};
    *(bf16x4*)(out + i * 4) = o;
  }
}

// Async-stage a 128x32 bf16 tile into contiguous LDS [128][32] via global_load_lds w16.
__device__ __forceinline__ void stage_async(const bf16_t* __restrict__ g, int ld,
                                            int row0, int k0, bf16_t* lds,
                                            int wave, int lane) {
#pragma unroll
  for (int t = 0; t < 2; ++t) {
    const int rb = (t * 4 + wave) * 16;
    const bf16_t* gp = g + (size_t)(row0 + rb + (lane >> 2)) * ld + (k0 + (lane & 3) * 8);
    __builtin_amdgcn_global_load_lds((glb_uint*)gp, (lds_uint*)(lds + rb * BK), 16, 0, 0);
  }
}

// Async-stage a 128x64 fp8 tile into contiguous LDS [128][64B] (row stride 64B).
__device__ __forceinline__ void stage_f8(const uint8_t* __restrict__ g, int ld,
                                         int row0, int k0, uint8_t* lds,
                                         int wave, int lane) {
#pragma unroll
  for (int t = 0; t < 2; ++t) {
    const int rb = (t * 4 + wave) * 16;
    const uint8_t* gp = g + (size_t)(row0 + rb + (lane >> 2)) * ld + (k0 + (lane & 3) * 16);
    __builtin_amdgcn_global_load_lds((glb_uint*)gp, (lds_uint*)(lds + rb * 64), 16, 0, 0);
  }
}

// h = x @ W^T + b, bf16, double-buffered; writes h (bf16, for scores) AND
// hT (fp8 e4m3, consumed only by the MX-fp8 pv kernel).  [round-0 body]
__global__ __launch_bounds__(256) void gemm1_kernel(const bf16_t* __restrict__ xb,
                                                    const bf16_t* __restrict__ Wb,
                                                    const float* __restrict__ bias,
                                                    bf16_t* __restrict__ hout,
                                                    uint8_t* __restrict__ hT8) {
  __shared__ __align__(16) bf16_t smem[4 * TILE_B];
  const int tid = threadIdx.x;
  const int wave = tid >> 6, lane = tid & 63;
  const int wm = wave >> 1, wn = wave & 1;
  const int l15 = lane & 15, quad = lane >> 4;
  const int m0 = blockIdx.x * 128, n0 = blockIdx.y * 128;
  f32x4 acc[4][4] = {};
  const int NIT = DFEAT / BK;
  stage_async(xb, DFEAT, m0, 0, smem, wave, lane);
  stage_async(Wb, DFEAT, n0, 0, smem + TILE_B, wave, lane);
  __syncthreads();
  for (int it = 0; it < NIT; ++it) {
    bf16_t* lA = smem + (it & 1) * 2 * TILE_B;
    bf16_t* lB = lA + TILE_B;
    if (it + 1 < NIT) {
      bf16_t* nA = smem + ((it + 1) & 1) * 2 * TILE_B;
      stage_async(xb, DFEAT, m0, (it + 1) * BK, nA, wave, lane);
      stage_async(Wb, DFEAT, n0, (it + 1) * BK, nA + TILE_B, wave, lane);
    }
    bf16x8 a[4], b[4];
#pragma unroll
    for (int f = 0; f < 4; ++f) {
      a[f] = *(const bf16x8*)(lA + (wm * 64 + f * 16 + l15) * BK + quad * 8);
      b[f] = *(const bf16x8*)(lB + (wn * 64 + f * 16 + l15) * BK + quad * 8);
    }
#pragma unroll
    for (int i = 0; i < 4; ++i)
#pragma unroll
      for (int j = 0; j < 4; ++j)
        acc[i][j] = __builtin_amdgcn_mfma_f32_16x16x32_bf16(a[i], b[j], acc[i][j], 0, 0, 0);
    __syncthreads();
  }
#pragma unroll
  for (int i = 0; i < 4; ++i) {
    int rbase = m0 + wm * 64 + i * 16 + quad * 4;
#pragma unroll
    for (int j = 0; j < 4; ++j) {
      int col = n0 + wn * 64 + j * 16 + l15;
      float bv = bias[col];
      float hv[4];
#pragma unroll
      for (int r = 0; r < 4; ++r) hv[r] = acc[i][j][r] + bv;
#pragma unroll
      for (int r = 0; r < 4; ++r)
        hout[(size_t)(rbase + r) * DFEAT + col] = (bf16_t)hv[r];
      *(unsigned*)(hT8 + (size_t)col * NROWS + rbase) =
          pack_fp8x4(hv[0], hv[1], hv[2], hv[3]);  // fused transpose, fp8
    }
  }
}

// Symmetric scores. This round: NO LDS STAGING in the K-loop. Each XCD's
// supertile working set (two 2 MB h-bands = 4 MB) is L2-resident by
// construction, so MFMA fragments are loaded directly global->VGPR
// (per-lane 16B global_load_dwordx4 in exact fragment layout), with a
// depth-1 register prefetch. Zero barriers, zero vmcnt drains, zero LDS
// traffic in the loop. LDS holds only the 18 KB mirror tile.
__global__ __launch_bounds__(256) void scores_sym_kernel(const bf16_t* __restrict__ h,
                                                         uint8_t* __restrict__ P,
                                                         float* __restrict__ lsum) {
  __shared__ __align__(16) uint8_t mir[128][144];  // mirror tile (row stride 144 = 9*16B)

  // supertile decode: id -> (bm, bn), bm <= bn
  const int k = (int)blockIdx.x & 7;   // XCD
  const int s = (int)blockIdx.x >> 3;  // slot 0..259
  int I, J, r, c;
  if (s < 36) {               // diagonal supertile (k,k): 36 upper-tri tiles
    I = J = k;
    int tt = s; r = 0;
    while (tt >= 8 - r) { tt -= 8 - r; ++r; }
    c = r + tt;
  } else {
    int e, t;
    if (s < 228) { e = 3 * k + (s - 36) / 64; t = (s - 36) & 63; }  // 3 full off-diag
    else { e = 24 + (k >> 1); t = ((k & 1) << 5) + (s - 228); }     // shared half
    int ee = e; I = 0;
    while (ee >= 7 - I) { ee -= 7 - I; ++I; }  // off-diag supertile e -> (I,J), I<J
    J = I + 1 + ee;
    r = t >> 3; c = t & 7;
  }
  const int bm = I * 8 + r, bn = J * 8 + c;
  const bool offdiag = (bm != bn);
  const int m0 = bm * 128, n0 = bn * 128;

  const int tid = threadIdx.x;
  const int wave = tid >> 6, lane = tid & 63;
  const int wm = wave >> 1, wn = wave & 1;
  const int l15 = lane & 15, quad = lane >> 4;

  // per-lane fragment base addresses (row = frag row, col chunk = quad*8)
  const bf16_t* ga = h + (size_t)(m0 + wm * 64 + l15) * DFEAT + quad * 8;
  const bf16_t* gb = h + (size_t)(n0 + wn * 64 + l15) * DFEAT + quad * 8;

  f32x4 acc[4][4] = {};
  const int NIT = DFEAT / BK;
  bf16x8 a[4], b[4];
#pragma unroll
  for (int f = 0; f < 4; ++f) {
    a[f] = *(const bf16x8*)(ga + f * 16 * DFEAT);
    b[f] = *(const bf16x8*)(gb + f * 16 * DFEAT);
  }
#pragma unroll 2
  for (int it = 0; it < NIT; ++it) {
    bf16x8 an[4], bn[4];
    if (it + 1 < NIT) {
      const int k1 = (it + 1) * BK;
#pragma unroll
      for (int f = 0; f < 4; ++f) {
        an[f] = *(const bf16x8*)(ga + f * 16 * DFEAT + k1);
        bn[f] = *(const bf16x8*)(gb + f * 16 * DFEAT + k1);
      }
    }
#pragma unroll
    for (int i = 0; i < 4; ++i)
#pragma unroll
      for (int j = 0; j < 4; ++j)
        acc[i][j] = __builtin_amdgcn_mfma_f32_16x16x32_bf16(a[i], b[j], acc[i][j], 0, 0, 0);
    if (it + 1 < NIT) {
#pragma unroll
      for (int f = 0; f < 4; ++f) { a[f] = an[f]; b[f] = bn[f]; }
    }
  }

  float rs[4][4];
  float cs[4];
#pragma unroll
  for (int i = 0; i < 4; ++i)
#pragma unroll
    for (int r2 = 0; r2 < 4; ++r2) rs[i][r2] = 0.f;
#pragma unroll
  for (int j = 0; j < 4; ++j) cs[j] = 0.f;

#pragma unroll
  for (int i = 0; i < 4; ++i) {
    const int rl_loc = wm * 64 + i * 16 + quad * 4;
    const int rbase = m0 + rl_loc;
#pragma unroll
    for (int j = 0; j < 4; ++j) {
      const int cl_loc = wn * 64 + j * 16 + l15;
      const int col = n0 + cl_loc;
      float p[4];
#pragma unroll
      for (int r2 = 0; r2 < 4; ++r2) p[r2] = __expf(fast_tanh(acc[i][j][r2]));
      unsigned packed = pack_fp8x4(p[0], p[1], p[2], p[3]);
      // dequantize for sums so the softmax denominator matches stored P
      f32x2 d0 = __builtin_amdgcn_cvt_pk_f32_fp8(packed, false);
      f32x2 d1 = __builtin_amdgcn_cvt_pk_f32_fp8(packed, true);
      float q[4] = {d0.x, d0.y, d1.x, d1.y};
#pragma unroll
      for (int r2 = 0; r2 < 4; ++r2) {
        rs[i][r2] += q[r2];
        cs[j] += q[r2];
        P[(size_t)(rbase + r2) * NROWS + col] = (uint8_t)(packed >> (8 * r2));
      }
      if (offdiag) *(unsigned*)&mir[cl_loc][rl_loc] = packed;
    }
  }

#pragma unroll
  for (int off = 1; off < 16; off <<= 1)
#pragma unroll
    for (int i = 0; i < 4; ++i)
#pragma unroll
      for (int r2 = 0; r2 < 4; ++r2) rs[i][r2] += __shfl_xor(rs[i][r2], off, 64);
  if (l15 == 0) {
#pragma unroll
    for (int i = 0; i < 4; ++i) {
      int rbase = m0 + wm * 64 + i * 16 + quad * 4;
#pragma unroll
      for (int r2 = 0; r2 < 4; ++r2) atomicAdd(&lsum[rbase + r2], rs[i][r2]);
    }
  }

  if (offdiag) {
#pragma unroll
    for (int off = 16; off < 64; off <<= 1)
#pragma unroll
      for (int j = 0; j < 4; ++j) cs[j] += __shfl_xor(cs[j], off, 64);
    if (quad == 0) {
#pragma unroll
      for (int j = 0; j < 4; ++j)
        atomicAdd(&lsum[n0 + wn * 64 + j * 16 + l15], cs[j]);
    }
    __syncthreads();  // all mirror writes visible before block-wide readback
#pragma unroll
    for (int it = 0; it < 4; ++it) {
      int q2 = tid + it * 256;          // 0..1023
      int c2 = q2 >> 3, r0 = (q2 & 7) * 16;
      uint4 v = *(const uint4*)(&mir[c2][r0]);
      *(uint4*)(P + (size_t)(n0 + c2) * NROWS + m0 + r0) = v;
    }
  }
}

// out = tanh((P @ h) / l): MX-fp8 (e4m3) MFMA with unity scales, K=64/iter,
// double-buffered staging. Grid (x=m=64, y=n=8) keeps same-m0 blocks on one
// XCD -> P strip L2-resident.  [round-0 body]
__global__ __launch_bounds__(256) void pv_kernel(const uint8_t* __restrict__ P,
                                                 const uint8_t* __restrict__ hT8,
                                                 const float* __restrict__ lsum,
                                                 float* __restrict__ out) {
  __shared__ __align__(16) uint8_t smem[4 * F8TILE];  // 2 phases x (A 8KB + B 8KB)
  const int tid = threadIdx.x;
  const int wave = tid >> 6, lane = tid & 63;
  const int wm = wave >> 1, wn = wave & 1;
  const int l31 = lane & 31, khalf = lane >> 5;
  const int m0 = blockIdx.x * 128, n0 = blockIdx.y * 128;
  f32x16 acc[2][2] = {};
  const int NIT = NROWS / 64;
  stage_f8(P, NROWS, m0, 0, smem, wave, lane);
  stage_f8(hT8, NROWS, n0, 0, smem + F8TILE, wave, lane);
  __syncthreads();
  for (int it = 0; it < NIT; ++it) {
    uint8_t* lA = smem + (it & 1) * 2 * F8TILE;
    uint8_t* lB = lA + F8TILE;
    if (it + 1 < NIT) {
      uint8_t* nA = smem + ((it + 1) & 1) * 2 * F8TILE;
      stage_f8(P, NROWS, m0, (it + 1) * 64, nA, wave, lane);
      stage_f8(hT8, NROWS, n0, (it + 1) * 64, nA + F8TILE, wave, lane);
    }
    i32x8 a[2], b[2];
#pragma unroll
    for (int f = 0; f < 2; ++f) {
      {
        int off = (wm * 64 + f * 32 + l31) * 64 + khalf * 32;
        i32x4 lo = *(const i32x4*)(lA + off);
        i32x4 hi = *(const i32x4*)(lA + off + 16);
        a[f] = i32x8{lo[0], lo[1], lo[2], lo[3], hi[0], hi[1], hi[2], hi[3]};
      }
      {
        int off = (wn * 64 + f * 32 + l31) * 64 + khalf * 32;
        i32x4 lo = *(const i32x4*)(lB + off);
        i32x4 hi = *(const i32x4*)(lB + off + 16);
        b[f] = i32x8{lo[0], lo[1], lo[2], lo[3], hi[0], hi[1], hi[2], hi[3]};
      }
    }
#pragma unroll
    for (int bi = 0; bi < 2; ++bi)
#pragma unroll
      for (int bj = 0; bj < 2; ++bj)
        acc[bi][bj] = __builtin_amdgcn_mfma_scale_f32_32x32x64_f8f6f4(
            a[bi], b[bj], acc[bi][bj], 0, 0, 0, 0x7F7F7F7F, 0, 0x7F7F7F7F);
    __syncthreads();
  }
  // C/D 32x32: col = lane&31, row = (reg&3) + 8*(reg>>2) + 4*(lane>>5)
#pragma unroll
  for (int bi = 0; bi < 2; ++bi)
#pragma unroll
    for (int bj = 0; bj < 2; ++bj) {
      int cbase = n0 + wn * 64 + bj * 32 + l31;
#pragma unroll
      for (int reg = 0; reg < 16; ++reg) {
        int row = m0 + wm * 64 + bi * 32 + (reg & 3) + 8 * (reg >> 2) + 4 * khalf;
        float rl = __builtin_amdgcn_rcpf(lsum[row]);
        out[(size_t)row * DFEAT + cbase] = fast_tanh(acc[bi][bj][reg] * rl);
      }
    }
}

extern "C" void kernel_launch(void* const* d_in, const int* in_sizes, int n_in,
                              void* d_out, int out_size, void* d_ws, size_t ws_size,
                              hipStream_t stream) {
  const float* x = (const float*)d_in[0];
  const float* W = (const float*)d_in[1];
  const float* bias = (const float*)d_in[2];
  float* out = (float*)d_out;

  bf16_t* xb = (bf16_t*)d_ws;                        // 16 MB
  bf16_t* Wb = xb + (size_t)NROWS * DFEAT;           // 2 MB
  bf16_t* h  = Wb + (size_t)DFEAT * DFEAT;           // 16 MB
  uint8_t* hT8 = (uint8_t*)(h + (size_t)NROWS * DFEAT);  // 8 MB (fp8)
  float* lsum = (float*)(hT8 + (size_t)DFEAT * NROWS);
  uint8_t* P = (uint8_t*)(lsum + NROWS);             // 67 MB (fp8)

  cast_kernel<<<(NROWS * DFEAT / 4) / 256, 256, 0, stream>>>(x, xb, NROWS * DFEAT / 4);
  cast_kernel<<<(DFEAT * DFEAT / 4) / 256, 256, 0, stream>>>(W, Wb, DFEAT * DFEAT / 4);
  gemm1_kernel<<<dim3(NROWS / 128, DFEAT / 128), 256, 0, stream>>>(xb, Wb, bias, h, hT8);
  hipMemsetAsync(lsum, 0, NROWS * sizeof(float), stream);
  scores_sym_kernel<<<NTRI, 256, 0, stream>>>(h, P, lsum);
  pv_kernel<<<dim3(NROWS / 128, DFEAT / 128), 256, 0, stream>>>(P, hT8, lsum, out);
}

// Round 4
// 314.729 us; speedup vs baseline: 1.4469x; 1.4469x over previous
//
#include <hip/hip_runtime.h>
#include <hip/hip_bf16.h>
#include <cstdint>
#include <cstddef>

typedef __bf16 bf16_t;
typedef __bf16 bf16x4 __attribute__((ext_vector_type(4)));
typedef __bf16 bf16x8 __attribute__((ext_vector_type(8)));
typedef float f32x4 __attribute__((ext_vector_type(4)));
typedef float f32x16 __attribute__((ext_vector_type(16)));
typedef float f32x2 __attribute__((ext_vector_type(2)));
typedef int i32x4 __attribute__((ext_vector_type(4)));
typedef int i32x8 __attribute__((ext_vector_type(8)));

#define NROWS 8192
#define DFEAT 1024
#define BK 32
#define NBLK 64            // NROWS/128 (gemm1/pv tiling)
#define TILE_B (128 * BK)  // bf16 elems per staged tile (8 KB)
#define F8TILE 8192        // fp8 bytes per staged 128x64 tile
#define NB2 32             // NROWS/256 (scores tiling)
#define NTRI2 528          // NB2*(NB2+1)/2 triangular 256^2 tiles

typedef __attribute__((address_space(3))) unsigned int lds_uint;
typedef __attribute__((address_space(1))) const unsigned int glb_uint;

__device__ __forceinline__ float fast_tanh(float x) {
  float e = __expf(2.0f * x);
  return 1.0f - 2.0f * __builtin_amdgcn_rcpf(e + 1.0f);
}

// pack 4 floats -> 4 fp8 e4m3 bytes (OCP, HW cvt)
__device__ __forceinline__ unsigned pack_fp8x4(float a, float b, float c, float d) {
  unsigned v = 0;
  v = __builtin_amdgcn_cvt_pk_fp8_f32(a, b, v, false);
  v = __builtin_amdgcn_cvt_pk_fp8_f32(c, d, v, true);
  return v;
}

__global__ __launch_bounds__(256) void cast_kernel(const float* __restrict__ in,
                                                   bf16_t* __restrict__ out, int n4) {
  int i = blockIdx.x * 256 + threadIdx.x;
  if (i < n4) {
    float4 v = *(const float4*)(in + i * 4);
    bf16x4 o = {(bf16_t)v.x, (bf16_t)v.y, (bf16_t)v.z, (bf16_t)v.w};
    *(bf16x4*)(out + i * 4) = o;
  }
}

// Async-stage a 128x32 bf16 tile into contiguous LDS [128][32] via global_load_lds w16.
__device__ __forceinline__ void stage_async(const bf16_t* __restrict__ g, int ld,
                                            int row0, int k0, bf16_t* lds,
                                            int wave, int lane) {
#pragma unroll
  for (int t = 0; t < 2; ++t) {
    const int rb = (t * 4 + wave) * 16;
    const bf16_t* gp = g + (size_t)(row0 + rb + (lane >> 2)) * ld + (k0 + (lane & 3) * 8);
    __builtin_amdgcn_global_load_lds((glb_uint*)gp, (lds_uint*)(lds + rb * BK), 16, 0, 0);
  }
}

// Async-stage a 128x64 fp8 tile into contiguous LDS [128][64B] (row stride 64B).
__device__ __forceinline__ void stage_f8(const uint8_t* __restrict__ g, int ld,
                                         int row0, int k0, uint8_t* lds,
                                         int wave, int lane) {
#pragma unroll
  for (int t = 0; t < 2; ++t) {
    const int rb = (t * 4 + wave) * 16;
    const uint8_t* gp = g + (size_t)(row0 + rb + (lane >> 2)) * ld + (k0 + (lane & 3) * 16);
    __builtin_amdgcn_global_load_lds((glb_uint*)gp, (lds_uint*)(lds + rb * 64), 16, 0, 0);
  }
}

// Async-stage a 256x64 bf16 tile (32 KB) into LDS via 4x global_load_lds w16
// per thread (8-wave/512-thread block). LDS dest is LINEAR [256][64]; the
// SOURCE 16B-chunk is XOR-swizzled so that LDS slot (row, c') holds global
// chunk c' ^ ((row>>1)&7). The matching XOR on ds_read gives a free 2-way
// bank pattern (adjacent row pairs share a bank) instead of 16-way.
__device__ __forceinline__ void stage256(const bf16_t* __restrict__ g,
                                         int row0, int kt, bf16_t* lds,
                                         int wave, int lane) {
  const int cg = (lane & 7) ^ ((wave * 4 + (lane >> 4)) & 7);  // swizzled global chunk
#pragma unroll
  for (int o = 0; o < 4; ++o) {
    const int row = o * 64 + wave * 8 + (lane >> 3);
    const bf16_t* gp = g + (size_t)(row0 + row) * DFEAT + kt * 64 + cg * 8;
    __builtin_amdgcn_global_load_lds((glb_uint*)gp,
        (lds_uint*)(lds + o * 4096 + wave * 512 + lane * 8), 16, 0, 0);
  }
}

// h = x @ W^T + b, bf16, double-buffered; writes h (bf16, for scores) AND
// hT (fp8 e4m3, consumed only by the MX-fp8 pv kernel).  [round-0 body]
__global__ __launch_bounds__(256) void gemm1_kernel(const bf16_t* __restrict__ xb,
                                                    const bf16_t* __restrict__ Wb,
                                                    const float* __restrict__ bias,
                                                    bf16_t* __restrict__ hout,
                                                    uint8_t* __restrict__ hT8) {
  __shared__ __align__(16) bf16_t smem[4 * TILE_B];
  const int tid = threadIdx.x;
  const int wave = tid >> 6, lane = tid & 63;
  const int wm = wave >> 1, wn = wave & 1;
  const int l15 = lane & 15, quad = lane >> 4;
  const int m0 = blockIdx.x * 128, n0 = blockIdx.y * 128;
  f32x4 acc[4][4] = {};
  const int NIT = DFEAT / BK;
  stage_async(xb, DFEAT, m0, 0, smem, wave, lane);
  stage_async(Wb, DFEAT, n0, 0, smem + TILE_B, wave, lane);
  __syncthreads();
  for (int it = 0; it < NIT; ++it) {
    bf16_t* lA = smem + (it & 1) * 2 * TILE_B;
    bf16_t* lB = lA + TILE_B;
    if (it + 1 < NIT) {
      bf16_t* nA = smem + ((it + 1) & 1) * 2 * TILE_B;
      stage_async(xb, DFEAT, m0, (it + 1) * BK, nA, wave, lane);
      stage_async(Wb, DFEAT, n0, (it + 1) * BK, nA + TILE_B, wave, lane);
    }
    bf16x8 a[4], b[4];
#pragma unroll
    for (int f = 0; f < 4; ++f) {
      a[f] = *(const bf16x8*)(lA + (wm * 64 + f * 16 + l15) * BK + quad * 8);
      b[f] = *(const bf16x8*)(lB + (wn * 64 + f * 16 + l15) * BK + quad * 8);
    }
#pragma unroll
    for (int i = 0; i < 4; ++i)
#pragma unroll
      for (int j = 0; j < 4; ++j)
        acc[i][j] = __builtin_amdgcn_mfma_f32_16x16x32_bf16(a[i], b[j], acc[i][j], 0, 0, 0);
    __syncthreads();
  }
#pragma unroll
  for (int i = 0; i < 4; ++i) {
    int rbase = m0 + wm * 64 + i * 16 + quad * 4;
#pragma unroll
    for (int j = 0; j < 4; ++j) {
      int col = n0 + wn * 64 + j * 16 + l15;
      float bv = bias[col];
      float hv[4];
#pragma unroll
      for (int r = 0; r < 4; ++r) hv[r] = acc[i][j][r] + bv;
#pragma unroll
      for (int r = 0; r < 4; ++r)
        hout[(size_t)(rbase + r) * DFEAT + col] = (bf16_t)hv[r];
      *(unsigned*)(hT8 + (size_t)col * NROWS + rbase) =
          pack_fp8x4(hv[0], hv[1], hv[2], hv[3]);  // fused transpose, fp8
    }
  }
}

// Symmetric scores, 256^2 tiles, 8 waves (2M x 4N), BK=64, T3-minimum
// 2-phase schedule: { stage(kt+1) -> ds_read(kt) -> MFMA(kt) -> barrier },
// one vmcnt-drain+barrier per K-tile, stage issued a full compute-phase
// before its drain. 2x arithmetic intensity vs the 128^2 structure (staged
// bytes per MFMA halved). LDS: 2 x (A 32KB + B 32KB) = 128 KB dbuf; the
// 256x256 fp8 mirror (69.6 KB) overlays it after the loop's final barrier.
// Supertile decode: 4x4-tile supertiles (1024-row bands, 4 MB = one XCD
// L2), XCD k (= blockIdx&7) runs its diagonal supertile (10 tiles) + 3 full
// off-diag (16 each) + half of a shared off-diag (8) = 66 slots.
__global__ __launch_bounds__(512, 1) void scores_sym_kernel(const bf16_t* __restrict__ h,
                                                            uint8_t* __restrict__ P,
                                                            float* __restrict__ lsum) {
  __shared__ __align__(16) char smem_raw[131072];
  bf16_t* smb = (bf16_t*)smem_raw;
  uint8_t (*mir)[272] = (uint8_t(*)[272])smem_raw;

  // supertile decode: id -> (bm, bn), bm <= bn (4x4 supertiles over 32 bands)
  const int k = (int)blockIdx.x & 7;   // XCD
  const int s = (int)blockIdx.x >> 3;  // slot 0..65
  int I, J, r, c;
  if (s < 10) {               // diagonal supertile (k,k): 10 upper-tri tiles
    I = J = k;
    int tt = s; r = 0;
    while (tt >= 4 - r) { tt -= 4 - r; ++r; }
    c = r + tt;
  } else {
    int e, t;
    if (s < 58) { e = 3 * k + (s - 10) / 16; t = (s - 10) & 15; }  // 3 full off-diag
    else { e = 24 + (k >> 1); t = ((k & 1) << 3) + (s - 58); }     // shared half
    int ee = e; I = 0;
    while (ee >= 7 - I) { ee -= 7 - I; ++I; }  // off-diag supertile e -> (I,J), I<J
    J = I + 1 + ee;
    r = t >> 2; c = t & 3;
  }
  const int bm = I * 4 + r, bn = J * 4 + c;
  const bool offdiag = (bm != bn);
  const int m0 = bm * 256, n0 = bn * 256;

  const int tid = threadIdx.x;
  const int wave = tid >> 6, lane = tid & 63;
  const int wm = wave >> 2, wn = wave & 3;   // 2 x 4 wave grid
  const int l15 = lane & 15, quad = lane >> 4;
  const int rkey = (l15 >> 1) & 7;           // read-side de-swizzle key

  f32x4 acc[8][4] = {};
  const int NKT = DFEAT / 64;  // 16 K-tiles

  stage256(h, m0, 0, smb, wave, lane);
  stage256(h, n0, 0, smb + 16384, wave, lane);
  __syncthreads();
  for (int kt = 0; kt < NKT; ++kt) {
    bf16_t* bufA = smb + (kt & 1) * 32768;
    bf16_t* bufB = bufA + 16384;
    if (kt + 1 < NKT) {
      bf16_t* nA = smb + ((kt + 1) & 1) * 32768;
      stage256(h, m0, kt + 1, nA, wave, lane);
      stage256(h, n0, kt + 1, nA + 16384, wave, lane);
    }
#pragma unroll
    for (int ks = 0; ks < 2; ++ks) {
      const int cp = ((ks * 4 + quad) ^ rkey) * 8;  // swizzled chunk (elems)
      bf16x8 a[8], b[4];
#pragma unroll
      for (int mf = 0; mf < 8; ++mf)
        a[mf] = *(const bf16x8*)(bufA + (wm * 128 + mf * 16 + l15) * 64 + cp);
#pragma unroll
      for (int nf = 0; nf < 4; ++nf)
        b[nf] = *(const bf16x8*)(bufB + (wn * 64 + nf * 16 + l15) * 64 + cp);
#pragma unroll
      for (int mf = 0; mf < 8; ++mf)
#pragma unroll
        for (int nf = 0; nf < 4; ++nf)
          acc[mf][nf] = __builtin_amdgcn_mfma_f32_16x16x32_bf16(a[mf], b[nf], acc[mf][nf], 0, 0, 0);
    }
    __syncthreads();  // drains kt+1's loads (issued ~full compute phase ago)
  }
  // final barrier ran: all staging reads complete; smem free for mirror

  float rs[8][4];
  float cs[4];
#pragma unroll
  for (int i = 0; i < 8; ++i)
#pragma unroll
    for (int r2 = 0; r2 < 4; ++r2) rs[i][r2] = 0.f;
#pragma unroll
  for (int j = 0; j < 4; ++j) cs[j] = 0.f;

#pragma unroll
  for (int i = 0; i < 8; ++i) {
    const int rl_loc = wm * 128 + i * 16 + quad * 4;
    const int rbase = m0 + rl_loc;
#pragma unroll
    for (int j = 0; j < 4; ++j) {
      const int cl_loc = wn * 64 + j * 16 + l15;
      const int col = n0 + cl_loc;
      float p[4];
#pragma unroll
      for (int r2 = 0; r2 < 4; ++r2) p[r2] = __expf(fast_tanh(acc[i][j][r2]));
      unsigned packed = pack_fp8x4(p[0], p[1], p[2], p[3]);
      // dequantize for sums so the softmax denominator matches stored P
      f32x2 d0 = __builtin_amdgcn_cvt_pk_f32_fp8(packed, false);
      f32x2 d1 = __builtin_amdgcn_cvt_pk_f32_fp8(packed, true);
      float q[4] = {d0.x, d0.y, d1.x, d1.y};
#pragma unroll
      for (int r2 = 0; r2 < 4; ++r2) {
        rs[i][r2] += q[r2];
        cs[j] += q[r2];
        P[(size_t)(rbase + r2) * NROWS + col] = (uint8_t)(packed >> (8 * r2));
      }
      if (offdiag) *(unsigned*)&mir[cl_loc][rl_loc] = packed;
    }
  }

#pragma unroll
  for (int off = 1; off < 16; off <<= 1)
#pragma unroll
    for (int i = 0; i < 8; ++i)
#pragma unroll
      for (int r2 = 0; r2 < 4; ++r2) rs[i][r2] += __shfl_xor(rs[i][r2], off, 64);
  if (l15 == 0) {
#pragma unroll
    for (int i = 0; i < 8; ++i) {
      int rbase = m0 + wm * 128 + i * 16 + quad * 4;
#pragma unroll
      for (int r2 = 0; r2 < 4; ++r2) atomicAdd(&lsum[rbase + r2], rs[i][r2]);
    }
  }

  if (offdiag) {
#pragma unroll
    for (int off = 16; off < 64; off <<= 1)
#pragma unroll
      for (int j = 0; j < 4; ++j) cs[j] += __shfl_xor(cs[j], off, 64);
    if (quad == 0) {
#pragma unroll
      for (int j = 0; j < 4; ++j)
        atomicAdd(&lsum[n0 + wn * 64 + j * 16 + l15], cs[j]);
    }
    __syncthreads();  // all mirror writes visible before block-wide readback
#pragma unroll
    for (int it = 0; it < 8; ++it) {
      int q2 = tid + it * 512;          // 0..4095
      int c2 = q2 >> 4, r0 = (q2 & 15) * 16;
      uint4 v = *(const uint4*)(&mir[c2][r0]);
      *(uint4*)(P + (size_t)(n0 + c2) * NROWS + m0 + r0) = v;
    }
  }
}

// out = tanh((P @ h) / l): MX-fp8 (e4m3) MFMA with unity scales, K=64/iter,
// double-buffered staging. Grid (x=m=64, y=n=8) keeps same-m0 blocks on one
// XCD -> P strip L2-resident.  [round-0 body]
__global__ __launch_bounds__(256) void pv_kernel(const uint8_t* __restrict__ P,
                                                 const uint8_t* __restrict__ hT8,
                                                 const float* __restrict__ lsum,
                                                 float* __restrict__ out) {
  __shared__ __align__(16) uint8_t smem[4 * F8TILE];  // 2 phases x (A 8KB + B 8KB)
  const int tid = threadIdx.x;
  const int wave = tid >> 6, lane = tid & 63;
  const int wm = wave >> 1, wn = wave & 1;
  const int l31 = lane & 31, khalf = lane >> 5;
  const int m0 = blockIdx.x * 128, n0 = blockIdx.y * 128;
  f32x16 acc[2][2] = {};
  const int NIT = NROWS / 64;
  stage_f8(P, NROWS, m0, 0, smem, wave, lane);
  stage_f8(hT8, NROWS, n0, 0, smem + F8TILE, wave, lane);
  __syncthreads();
  for (int it = 0; it < NIT; ++it) {
    uint8_t* lA = smem + (it & 1) * 2 * F8TILE;
    uint8_t* lB = lA + F8TILE;
    if (it + 1 < NIT) {
      uint8_t* nA = smem + ((it + 1) & 1) * 2 * F8TILE;
      stage_f8(P, NROWS, m0, (it + 1) * 64, nA, wave, lane);
      stage_f8(hT8, NROWS, n0, (it + 1) * 64, nA + F8TILE, wave, lane);
    }
    i32x8 a[2], b[2];
#pragma unroll
    for (int f = 0; f < 2; ++f) {
      {
        int off = (wm * 64 + f * 32 + l31) * 64 + khalf * 32;
        i32x4 lo = *(const i32x4*)(lA + off);
        i32x4 hi = *(const i32x4*)(lA + off + 16);
        a[f] = i32x8{lo[0], lo[1], lo[2], lo[3], hi[0], hi[1], hi[2], hi[3]};
      }
      {
        int off = (wn * 64 + f * 32 + l31) * 64 + khalf * 32;
        i32x4 lo = *(const i32x4*)(lB + off);
        i32x4 hi = *(const i32x4*)(lB + off + 16);
        b[f] = i32x8{lo[0], lo[1], lo[2], lo[3], hi[0], hi[1], hi[2], hi[3]};
      }
    }
#pragma unroll
    for (int bi = 0; bi < 2; ++bi)
#pragma unroll
      for (int bj = 0; bj < 2; ++bj)
        acc[bi][bj] = __builtin_amdgcn_mfma_scale_f32_32x32x64_f8f6f4(
            a[bi], b[bj], acc[bi][bj], 0, 0, 0, 0x7F7F7F7F, 0, 0x7F7F7F7F);
    __syncthreads();
  }
  // C/D 32x32: col = lane&31, row = (reg&3) + 8*(reg>>2) + 4*(lane>>5)
#pragma unroll
  for (int bi = 0; bi < 2; ++bi)
#pragma unroll
    for (int bj = 0; bj < 2; ++bj) {
      int cbase = n0 + wn * 64 + bj * 32 + l31;
#pragma unroll
      for (int reg = 0; reg < 16; ++reg) {
        int row = m0 + wm * 64 + bi * 32 + (reg & 3) + 8 * (reg >> 2) + 4 * khalf;
        float rl = __builtin_amdgcn_rcpf(lsum[row]);
        out[(size_t)row * DFEAT + cbase] = fast_tanh(acc[bi][bj][reg] * rl);
      }
    }
}

extern "C" void kernel_launch(void* const* d_in, const int* in_sizes, int n_in,
                              void* d_out, int out_size, void* d_ws, size_t ws_size,
                              hipStream_t stream) {
  const float* x = (const float*)d_in[0];
  const float* W = (const float*)d_in[1];
  const float* bias = (const float*)d_in[2];
  float* out = (float*)d_out;

  bf16_t* xb = (bf16_t*)d_ws;                        // 16 MB
  bf16_t* Wb = xb + (size_t)NROWS * DFEAT;           // 2 MB
  bf16_t* h  = Wb + (size_t)DFEAT * DFEAT;           // 16 MB
  uint8_t* hT8 = (uint8_t*)(h + (size_t)NROWS * DFEAT);  // 8 MB (fp8)
  float* lsum = (float*)(hT8 + (size_t)DFEAT * NROWS);
  uint8_t* P = (uint8_t*)(lsum + NROWS);             // 67 MB (fp8)

  cast_kernel<<<(NROWS * DFEAT / 4) / 256, 256, 0, stream>>>(x, xb, NROWS * DFEAT / 4);
  cast_kernel<<<(DFEAT * DFEAT / 4) / 256, 256, 0, stream>>>(W, Wb, DFEAT * DFEAT / 4);
  gemm1_kernel<<<dim3(NROWS / 128, DFEAT / 128), 256, 0, stream>>>(xb, Wb, bias, h, hT8);
  hipMemsetAsync(lsum, 0, NROWS * sizeof(float), stream);
  scores_sym_kernel<<<NTRI2, 512, 0, stream>>>(h, P, lsum);
  pv_kernel<<<dim3(NROWS / 128, DFEAT / 128), 256, 0, stream>>>(P, hT8, lsum, out);
}